// Round 5
// baseline (126.323 us; speedup 1.0000x reference)
//
#include <hip/hip_runtime.h>
#include <math.h>

// Problem constants (reference: B,F,W,H,D = 128,1024,32,64,64)
#define B_   128
#define F_   1024
#define W_   32
#define H_   64
#define K4H  256          // 4*H
#define M_   (B_ * W_)    // 4096 rows of the gate GEMM
#define K2_  (2 * F_)     // 2048: fp32 split into interleaved (hi,lo) bf16 pairs

typedef __attribute__((ext_vector_type(8))) short  short8;  // 8 bf16 (MFMA A/B frag)
typedef __attribute__((ext_vector_type(4))) float  f32x4;   // MFMA C/D frag

// ---------------------------------------------------------------------------
// fp32 -> (hi,lo) bf16 pair packed into one uint: short[0]=hi (k2 even),
// short[1]=lo (k2 odd). hi=RNE(v), lo=RNE(v-hi) -> fp32 product via plain
// bf16 MFMA over doubled K, near-exact (~2^-17 relative).
// ---------------------------------------------------------------------------
__device__ __forceinline__ unsigned bf16_rne(float v) {
  unsigned u = __float_as_uint(v);
  return (u + 0x7FFFu + ((u >> 16) & 1u)) >> 16;
}
__device__ __forceinline__ unsigned pack_hilo(float v) {
  unsigned hi = bf16_rne(v);
  float    hf = __uint_as_float(hi << 16);
  unsigned lo = bf16_rne(v - hf);
  return hi | (lo << 16);
}

// ---------------------------------------------------------------------------
// Gate GEMM via MFMA (attention softmax over size-1 axis == 1, so the input
// projection is h-independent and hoisted out of the recurrence).
// Block tile 128(M)x128(N), 4 waves with 64x64 wave tiles (4x4 of 16x16x32
// bf16 MFMAs = 32 MFMA/stage), K-split S. Grid (32, 2, S) = 256 blocks @S=4.
// BOTH x and Wx are converted to hi/lo bf16 during LDS staging (conv_w
// kernel folded away: Wx is 1 MB, the per-XCD redundant re-read is ~1 us).
// 36-uint row stride keeps frag reads conflict-free (0 conflicts measured).
// __launch_bounds__(256,1): VGPR cap 512 -> nothing spills.
// ---------------------------------------------------------------------------
template <int S>
__global__ __launch_bounds__(256, 1) void gemm_mfma(
    const float* __restrict__ x,      // [B, F, W]
    const float* __restrict__ Wx,     // [F, 4H]
    float* __restrict__ Gp) {         // [S][M][4H] partials
  constexpr int NIT = 32 / S;         // stage iters of 32 f (64 k2) each
  __shared__ unsigned lA[128 * 36];   // [m][k2-pair fl]
  __shared__ unsigned lB[128 * 36];   // [n][k2-pair fl]
  const int tid   = threadIdx.x;
  const int mtile = blockIdx.x;       // 0..31 (4 batches per tile)
  const int ntile = blockIdx.y;       // 0..1  (128 gate cols)
  const int s     = blockIdx.z;       // 0..S-1
  const int wv = tid >> 6, lane = tid & 63;
  const int wm = wv & 1, wn = wv >> 1;      // wave -> 64x64 quadrant
  const int lm = lane & 15, q = lane >> 4;  // MFMA lane decomposition

  f32x4 acc[4][4];
#pragma unroll
  for (int a = 0; a < 4; ++a)
#pragma unroll
    for (int bb = 0; bb < 4; ++bb) acc[a][bb] = (f32x4){0.f, 0.f, 0.f, 0.f};

  const int b0 = mtile * 4;
  float4 ax[4];   // x staging (4 b x 32 f x 8 t-groups)
  float4 bx[4];   // Wx staging (32 f x 32 col-groups)

  auto prefetch = [&](int iter) {
    const int f0 = (s * NIT + iter) * 32;
#pragma unroll
    for (int i = 0; i < 4; ++i) {
      int l  = tid + i * 256;       // 1024 float4
      int t0 = (l & 7) * 4;
      int fl = (l >> 3) & 31;
      int bl = l >> 8;
      ax[i] = *(const float4*)&x[(((size_t)(b0 + bl)) * F_ + (f0 + fl)) * W_ + t0];
    }
#pragma unroll
    for (int i = 0; i < 4; ++i) {
      int l    = tid + i * 256;     // 1024 float4 = 32 f x 32 col4
      int col4 = l & 31;            // 4 cols each
      int fl   = l >> 5;            // 0..31
      bx[i] = *(const float4*)&Wx[(size_t)(f0 + fl) * K4H + ntile * 128 + col4 * 4];
    }
  };

  prefetch(0);
  for (int iter = 0; iter < NIT; ++iter) {
    __syncthreads();                 // previous iter's frag reads done
#pragma unroll
    for (int i = 0; i < 4; ++i) {    // A: convert + transpose (t -> row m)
      int l  = tid + i * 256;
      int t0 = (l & 7) * 4;
      int fl = (l >> 3) & 31;
      int bl = l >> 8;
      int m0 = bl * 32 + t0;
      lA[(m0 + 0) * 36 + fl] = pack_hilo(ax[i].x);
      lA[(m0 + 1) * 36 + fl] = pack_hilo(ax[i].y);
      lA[(m0 + 2) * 36 + fl] = pack_hilo(ax[i].z);
      lA[(m0 + 3) * 36 + fl] = pack_hilo(ax[i].w);
    }
#pragma unroll
    for (int i = 0; i < 4; ++i) {    // B: convert + transpose (col -> row n)
      int l    = tid + i * 256;
      int col4 = l & 31;
      int fl   = l >> 5;
      int n0   = col4 * 4;
      lB[(n0 + 0) * 36 + fl] = pack_hilo(bx[i].x);
      lB[(n0 + 1) * 36 + fl] = pack_hilo(bx[i].y);
      lB[(n0 + 2) * 36 + fl] = pack_hilo(bx[i].z);
      lB[(n0 + 3) * 36 + fl] = pack_hilo(bx[i].w);
    }
    __syncthreads();
    if (iter + 1 < NIT) prefetch(iter + 1);  // overlap globals with MFMA
#pragma unroll
    for (int step = 0; step < 2; ++step) {   // 2 x K2=32 MFMA steps
      short8 aF[4], bF[4];
#pragma unroll
      for (int mt = 0; mt < 4; ++mt) {
        int row = wm * 64 + mt * 16 + lm;    // A[m=lane&15][k=q*8+j]
        aF[mt] = *(const short8*)&lA[row * 36 + step * 16 + q * 4];
      }
#pragma unroll
      for (int nt = 0; nt < 4; ++nt) {
        int row = wn * 64 + nt * 16 + lm;    // B[k=q*8+j][n=lane&15]
        bF[nt] = *(const short8*)&lB[row * 36 + step * 16 + q * 4];
      }
#pragma unroll
      for (int mt = 0; mt < 4; ++mt)
#pragma unroll
        for (int nt = 0; nt < 4; ++nt)
          acc[mt][nt] = __builtin_amdgcn_mfma_f32_16x16x32_bf16(
              aF[mt], bF[nt], acc[mt][nt], 0, 0, 0);
    }
  }
  // epilogue: C/D layout col=lane&15, row=q*4+reg  [m89-verified]
  float* Gs = Gp + (size_t)s * ((size_t)M_ * K4H);
#pragma unroll
  for (int mt = 0; mt < 4; ++mt)
#pragma unroll
    for (int nt = 0; nt < 4; ++nt)
#pragma unroll
      for (int r = 0; r < 4; ++r) {
        int m = mtile * 128 + wm * 64 + mt * 16 + q * 4 + r;
        int n = ntile * 128 + wn * 64 + nt * 16 + lm;
        Gs[(size_t)m * K4H + n] = acc[mt][nt][r];
      }
}

// ---------------------------------------------------------------------------
// Sequential LSTM: 256 threads (4 waves) per batch element. Thread (w,u)
// owns ONE gate column k = w*64+u (wave 0/1/2/3 = i/f/g/o; tanh branch is
// wave-uniform). 64 Wh weights per thread stay register-resident (~100 VGPR
// total, no spill -- the 128/256-weight variants spilled at VGPR=80/144).
// h replicated per wave (lane u = h[u]); dot via v_readlane broadcast with
// 4 split FMA chains. One barrier/step (parity-double-buffered activation
// exchange); c,h updated redundantly in all waves. G partials prefetched
// TWO steps ahead so the ~900-cyc cross-XCD load never stalls the ~450-cyc
// step. Output = CELL state (reference's s,h swap).
// ---------------------------------------------------------------------------
__device__ __forceinline__ float bcastlane(float v, int l) {
  return __uint_as_float(__builtin_amdgcn_readlane(__float_as_uint(v), l));
}
__device__ __forceinline__ float sigm(float v)   { return 1.f / (1.f + __expf(-v)); }
__device__ __forceinline__ float tanh_f(float v) { return 1.f - 2.f / (__expf(2.f * v) + 1.f); }

template <int S>
__global__ __launch_bounds__(256, 1) void lstm_seq(
    const float* __restrict__ Gp, const float* __restrict__ Wh,
    const float* __restrict__ bl, float* __restrict__ out) {
  __shared__ float sact[2][4][64];            // [t-parity][gate-wave][u]
  const int b = blockIdx.x, tid = threadIdx.x;
  const int w = tid >> 6, u = tid & 63;
  const int k = w * 64 + u;                   // gate column

  float wc[64];                               // Wh column k, register-resident
#pragma unroll
  for (int j = 0; j < 64; ++j) wc[j] = Wh[j * K4H + k];
  const float bk = bl[k];
  const size_t base = (size_t)b * W_ * K4H + k;
  const size_t sstr = (size_t)M_ * K4H;

  float h = 0.f, c = 0.f;
  float pv[S], n1[S];                         // depth-2 prefetch pipeline
#pragma unroll
  for (int ss = 0; ss < S; ++ss) {
    pv[ss] = Gp[ss * sstr + base];                      // t = 0
    n1[ss] = Gp[ss * sstr + base + K4H];                // t = 1 (W_ >= 2)
  }

  for (int t = 0; t < W_; ++t) {
    float n2[S];
#pragma unroll
    for (int ss = 0; ss < S; ++ss)            // issue loads for t+2 NOW
      n2[ss] = (t + 2 < W_) ? Gp[ss * sstr + base + (size_t)(t + 2) * K4H] : 0.f;

    float a0 = bk, a1 = 0.f, a2 = 0.f, a3 = 0.f;
#pragma unroll
    for (int ss = 0; ss < S; ++ss) a0 += pv[ss];
#pragma unroll
    for (int j = 0; j < 64; j += 4) {         // 4 independent FMA chains
      a0 = fmaf(bcastlane(h, j),     wc[j],     a0);
      a1 = fmaf(bcastlane(h, j + 1), wc[j + 1], a1);
      a2 = fmaf(bcastlane(h, j + 2), wc[j + 2], a2);
      a3 = fmaf(bcastlane(h, j + 3), wc[j + 3], a3);
    }
    float g = (a0 + a1) + (a2 + a3);
    float act = (w == 2) ? tanh_f(g) : sigm(g);   // wave-uniform branch
    sact[t & 1][w][u] = act;
    __syncthreads();                          // the single barrier per step
    float si = sact[t & 1][0][u];
    float sf = sact[t & 1][1][u];
    float tg = sact[t & 1][2][u];
    float so = sact[t & 1][3][u];
    c = fmaf(sf, c, si * tg);                 // replicated in all 4 waves
    h = so * tanh_f(c);
    if (w == 0) out[((size_t)b * W_ + t) * H_ + u] = c;  // cell state out
#pragma unroll
    for (int ss = 0; ss < S; ++ss) { pv[ss] = n1[ss]; n1[ss] = n2[ss]; }
  }
}

// ---------------------------------------------------------------------------
extern "C" void kernel_launch(void* const* d_in, const int* in_sizes, int n_in,
                              void* d_out, int out_size, void* d_ws, size_t ws_size,
                              hipStream_t stream) {
  // 0:x 1:W_state 2:b_state 3:W_in 4:w_attn 5:b_attn 6:Wx 7:Wh 8:b_lstm
  const float* x      = (const float*)d_in[0];
  const float* Wx     = (const float*)d_in[6];
  const float* Wh     = (const float*)d_in[7];
  const float* b_lstm = (const float*)d_in[8];
  float* out = (float*)d_out;
  float* Gp  = (float*)d_ws;

  const size_t gbytes = (size_t)M_ * K4H * sizeof(float);  // 4 MB per partial

  if (ws_size >= 4 * gbytes) {                  // S = 4: 256 gemm blocks
    gemm_mfma<4><<<dim3(32, 2, 4), dim3(256), 0, stream>>>(x, Wx, Gp);
    lstm_seq<4> <<<dim3(B_),       dim3(256), 0, stream>>>(Gp, Wh, b_lstm, out);
  } else if (ws_size >= 2 * gbytes) {           // S = 2
    gemm_mfma<2><<<dim3(32, 2, 2), dim3(256), 0, stream>>>(x, Wx, Gp);
    lstm_seq<2> <<<dim3(B_),       dim3(256), 0, stream>>>(Gp, Wh, b_lstm, out);
  } else {                                      // S = 1 fallback (4 MB ws)
    gemm_mfma<1><<<dim3(32, 2, 1), dim3(256), 0, stream>>>(x, Wx, Gp);
    lstm_seq<1> <<<dim3(B_),       dim3(256), 0, stream>>>(Gp, Wh, b_lstm, out);
  }
}